// Round 1
// baseline (217.283 us; speedup 1.0000x reference)
//
#include <hip/hip_runtime.h>
#include <cstdio>

// CapsuleLayer dynamic routing, MI355X (gfx950).
// Design notes (round 0):
//  - u_hat recomputed per routing pass via MFMA (never materialized in HBM).
//  - logits b_t = u_hat . S where S = sum of previous outputs (linearity) -> no b tensor.
//  - mfma_f32_32x32x8bf16_1k x2 per K=16 (documented CDNA2 layouts, low layout risk).
//  - Swapped orientation: D[m=jd][n=b]; s accumulated in registers, partials fp16 in ws.

#define B_TOT 64
#define IC    2048
#define KD    16
#define NC    32
#define OD    16
#define JD    512           // NC*OD
#define NIC   256           // i-chunks
#define IPB   (IC/NIC)      // 8 capsules per block
#define EPS_SQ 1e-7f

typedef __attribute__((ext_vector_type(4)))  short s16x4;
typedef __attribute__((ext_vector_type(8)))  short s16x8;
typedef __attribute__((ext_vector_type(16))) float f32x16;

__device__ inline short bfc(float f) {
  // fp32 -> bf16 (RNE), bit pattern as short
  unsigned u = __builtin_bit_cast(unsigned, f);
  unsigned r = (u + 0x7FFFu + ((u >> 16) & 1u)) >> 16;
  return (short)(unsigned short)r;
}

__device__ inline f32x16 fz16() {
  f32x16 z;
#pragma unroll
  for (int q = 0; q < 16; q++) z[q] = 0.f;
  return z;
}

// ---------------------------------------------------------------------------
// Pack x (fp32 [64][2048][16]) into MFMA B-fragments (bf16), layout:
// xpack[i][bg][lane][e], e0-3: k=4*hi+e ; e4-7: k=8+4*hi+e  (hi = lane>>5)
// ---------------------------------------------------------------------------
__global__ __launch_bounds__(256) void k_prep(const float* __restrict__ x,
                                              unsigned short* __restrict__ xp) {
  int t = blockIdx.x * 256 + threadIdx.x;   // over IC*2*64 = 262144
  int l  = t & 63;
  int bg = (t >> 6) & 1;
  int i  = t >> 7;
  int b  = bg * 32 + (l & 31);
  int hi = l >> 5;
  const float* s = x + ((size_t)b * IC + i) * KD + 4 * hi;
  float4 v0 = *(const float4*)(s);
  float4 v1 = *(const float4*)(s + 8);
  s16x8 r;
  r[0] = bfc(v0.x); r[1] = bfc(v0.y); r[2] = bfc(v0.z); r[3] = bfc(v0.w);
  r[4] = bfc(v1.x); r[5] = bfc(v1.y); r[6] = bfc(v1.z); r[7] = bfc(v1.w);
  *(s16x8*)(xp + (size_t)t * 8) = r;
}

// ---------------------------------------------------------------------------
// One routing pass. Grid 512 blocks (bg = bid&1, ic = bid>>1), 256 thr (4 waves).
// Wave w owns jd-tiles mt = 4w..4w+3 (32 jd each). Lane: col=l&31 -> b local.
// D[m][n] = sum_k W[i, jd=mt*32+m, k] * x[b=bg*32+n, i, k]  (u_hat)
// FIRST pass: c = 1/32 uniform -> pure MFMA accumulate.
// ---------------------------------------------------------------------------
template <bool FIRST>
__global__ __launch_bounds__(256, 2) void k_pass(const float* __restrict__ W,
                                                 const unsigned short* __restrict__ xp,
                                                 const float* __restrict__ ST,
                                                 _Float16* __restrict__ part) {
  __shared__ float lg[32][33];   // [j][b-local]: logits, then softmax c (in place)
  const int bid = blockIdx.x;
  const int bg  = bid & 1;
  const int ic  = bid >> 1;
  const int tid = threadIdx.x;
  const int w   = tid >> 6;
  const int l   = tid & 63;
  const int col = l & 31;
  const int hi  = l >> 5;

  f32x16 sa[4];
#pragma unroll
  for (int m = 0; m < 4; m++) sa[m] = fz16();

  float Sv[4][16];
  if (!FIRST) {
#pragma unroll
    for (int m = 0; m < 4; m++) {
      int mt = w * 4 + m;
#pragma unroll
      for (int r = 0; r < 16; r++) {
        int row = (r & 3) + 8 * (r >> 2) + 4 * hi;
        Sv[m][r] = ST[(size_t)(mt * 32 + row) * 64 + bg * 32 + col];
      }
    }
  }

  for (int ii = 0; ii < IPB; ii++) {
    int i = ic * IPB + ii;
    s16x8 xv  = *(const s16x8*)(xp + ((size_t)i * 2 + bg) * 512 + (size_t)l * 8);
    s16x4 xlo = __builtin_shufflevector(xv, xv, 0, 1, 2, 3);
    s16x4 xhi = __builtin_shufflevector(xv, xv, 4, 5, 6, 7);

    f32x16 D[4];
#pragma unroll
    for (int m = 0; m < 4; m++) {
      int mt = w * 4 + m;
      int jd = mt * 32 + col;              // A-row index (l&31)
      const float* wp = W + ((size_t)i * JD + jd) * KD + 4 * hi;
      float4 a0 = *(const float4*)(wp);
      float4 a1 = *(const float4*)(wp + 8);
      s16x4 w0; w0[0]=bfc(a0.x); w0[1]=bfc(a0.y); w0[2]=bfc(a0.z); w0[3]=bfc(a0.w);
      s16x4 w1; w1[0]=bfc(a1.x); w1[1]=bfc(a1.y); w1[2]=bfc(a1.z); w1[3]=bfc(a1.w);
      f32x16 acc = FIRST ? sa[m] : fz16();
      acc = __builtin_amdgcn_mfma_f32_32x32x8bf16_1k(w0, xlo, acc, 0, 0, 0);
      acc = __builtin_amdgcn_mfma_f32_32x32x8bf16_1k(w1, xhi, acc, 0, 0, 0);
      if (FIRST) sa[m] = acc; else D[m] = acc;
    }

    if (!FIRST) {
      // logits: logit[b, j] = sum_d u_hat * S ; rows r<8 -> j even, r>=8 -> j odd
#pragma unroll
      for (int m = 0; m < 4; m++) {
        float pe = 0.f, po = 0.f;
#pragma unroll
        for (int r = 0; r < 8; r++)  pe += D[m][r] * Sv[m][r];
#pragma unroll
        for (int r = 8; r < 16; r++) po += D[m][r] * Sv[m][r];
        pe += __shfl_xor(pe, 32);   // other d-half lives in lane^32
        po += __shfl_xor(po, 32);
        int mt = w * 4 + m;
        if (l < 32) { lg[2 * mt][col] = pe; lg[2 * mt + 1][col] = po; }
      }
      __syncthreads();
      // softmax over j=32 per b: wave w handles b-local 8w..8w+7, 8 lanes per b
      {
        int bb = w * 8 + (l >> 3);
        int sub = l & 7;
        float v0 = lg[sub * 4 + 0][bb], v1 = lg[sub * 4 + 1][bb];
        float v2 = lg[sub * 4 + 2][bb], v3 = lg[sub * 4 + 3][bb];
        float mx = fmaxf(fmaxf(v0, v1), fmaxf(v2, v3));
        mx = fmaxf(mx, __shfl_xor(mx, 1));
        mx = fmaxf(mx, __shfl_xor(mx, 2));
        mx = fmaxf(mx, __shfl_xor(mx, 4));
        v0 = __expf(v0 - mx); v1 = __expf(v1 - mx);
        v2 = __expf(v2 - mx); v3 = __expf(v3 - mx);
        float sm = v0 + v1 + v2 + v3;
        sm += __shfl_xor(sm, 1);
        sm += __shfl_xor(sm, 2);
        sm += __shfl_xor(sm, 4);
        float iv = 1.0f / sm;
        lg[sub * 4 + 0][bb] = v0 * iv; lg[sub * 4 + 1][bb] = v1 * iv;
        lg[sub * 4 + 2][bb] = v2 * iv; lg[sub * 4 + 3][bb] = v3 * iv;
      }
      __syncthreads();
      // s += c * u_hat (pure register FMA; lane<->(b,jd) mapping fixed)
#pragma unroll
      for (int m = 0; m < 4; m++) {
        int mt = w * 4 + m;
        float ce = lg[2 * mt][col];
        float co = lg[2 * mt + 1][col];
#pragma unroll
        for (int r = 0; r < 8; r++)  sa[m][r] += ce * D[m][r];
#pragma unroll
        for (int r = 8; r < 16; r++) sa[m][r] += co * D[m][r];
      }
      __syncthreads();   // protect lg before next i overwrites it
    }
  }

  const float sc = FIRST ? (1.0f / 32.0f) : 1.0f;
#pragma unroll
  for (int m = 0; m < 4; m++) {
    int mt = w * 4 + m;
#pragma unroll
    for (int r = 0; r < 16; r++) {
      int row = (r & 3) + 8 * (r >> 2) + 4 * hi;
      int jd = mt * 32 + row;
      part[(((size_t)bg * JD + jd) * NIC + ic) * 32 + col] = (_Float16)(sa[m][r] * sc);
    }
  }
}

// ---------------------------------------------------------------------------
// Reduce partials over ic, squash, update S (cumulative outputs) / final out.
// Grid 64 blocks (bg = bid&1, j = bid>>1), 512 threads (b = t&31, d = t>>5).
// ---------------------------------------------------------------------------
template <bool FIRST, bool FINAL>
__global__ __launch_bounds__(512) void k_squash(const _Float16* __restrict__ part,
                                                float* __restrict__ ST,
                                                float* __restrict__ out) {
  __shared__ float sl[16][33];
  int bid = blockIdx.x;
  int bg = bid & 1, j = bid >> 1;
  int t = threadIdx.x;
  int b = t & 31, d = t >> 5;
  int jd = j * 16 + d;
  const _Float16* p = part + (((size_t)bg * JD + jd) * NIC) * 32 + b;
  float a0 = 0.f, a1 = 0.f, a2 = 0.f, a3 = 0.f;
  for (int q = 0; q < NIC; q += 4) {
    a0 += (float)p[(size_t)(q + 0) * 32];
    a1 += (float)p[(size_t)(q + 1) * 32];
    a2 += (float)p[(size_t)(q + 2) * 32];
    a3 += (float)p[(size_t)(q + 3) * 32];
  }
  float s = (a0 + a1) + (a2 + a3);
  sl[d][b] = s * s;
  __syncthreads();
  float s2 = 0.f;
#pragma unroll
  for (int dd = 0; dd < 16; dd++) s2 += sl[dd][b];
  float o = s * s2 / ((1.0f + s2) * sqrtf(s2 + EPS_SQ));
  if (FINAL) {
    out[((size_t)(bg * 32 + b) * NC + j) * OD + d] = o;
  } else if (FIRST) {
    ST[(size_t)jd * 64 + bg * 32 + b] = o;
  } else {
    ST[(size_t)jd * 64 + bg * 32 + b] += o;
  }
}

// ---------------------------------------------------------------------------
extern "C" void kernel_launch(void* const* d_in, const int* in_sizes, int n_in,
                              void* d_out, int out_size, void* d_ws, size_t ws_size,
                              hipStream_t stream) {
  (void)in_sizes; (void)n_in; (void)out_size;
  const float* x = (const float*)d_in[0];
  const float* W = (const float*)d_in[1];
  float* out = (float*)d_out;

  const size_t off_xp = 0;                         // 4 MB  (bf16 x fragments)
  const size_t off_st = (size_t)4 << 20;           // 128 KB (S_T [jd][b] fp32)
  const size_t off_pt = off_st + ((size_t)256 << 10);
  const size_t need = off_pt + (size_t)2 * JD * NIC * 32 * sizeof(_Float16) + 1024;
  fprintf(stderr, "[caps] ws_size=%zu need=%zu\n", ws_size, need);
  if (ws_size < need) return;   // signal: absmax will fail; ws= line tells us why

  unsigned short* xp = (unsigned short*)((char*)d_ws + off_xp);
  float*          ST = (float*)((char*)d_ws + off_st);
  _Float16*     part = (_Float16*)((char*)d_ws + off_pt);

  k_prep<<<dim3(1024), dim3(256), 0, stream>>>(x, xp);

  // routing pass 0 (uniform c = 1/32)
  k_pass<true><<<dim3(512), dim3(256), 0, stream>>>(W, xp, ST, part);
  k_squash<true, false><<<dim3(64), dim3(512), 0, stream>>>(part, ST, out);
  // routing pass 1 (S = out0)
  k_pass<false><<<dim3(512), dim3(256), 0, stream>>>(W, xp, ST, part);
  k_squash<false, false><<<dim3(64), dim3(512), 0, stream>>>(part, ST, out);
  // routing pass 2 (S = out0 + out1) -> final outputs
  k_pass<false><<<dim3(512), dim3(256), 0, stream>>>(W, xp, ST, part);
  k_squash<false, true><<<dim3(64), dim3(512), 0, stream>>>(part, ST, out);
}

// Round 2
// 190.182 us; speedup vs baseline: 1.1425x; 1.1425x over previous
//
#include <hip/hip_runtime.h>
#include <cstdio>

// CapsuleLayer dynamic routing, MI355X (gfx950). Round 2.
//  - Round-1 diagnosis: k_pass W loads were 32-line gathers (lane stride 64 B)
//    -> TA transaction serialization (MfmaUtil 3%, VALUBusy 15%, 15k cyc/iter).
//  - Fix: pre-pack W into bf16 MFMA A-fragments once (coalesced via LDS bounce);
//    k_pass W loads become 16 B/lane contiguous. Sv kept packed bf16 (32 VGPR).
//  - k_squash split into k_red (512 blocks) + k_squash2 (tiny) - round 1 ran
//    the 256-iteration reduction on 64 blocks = 1/4 of the CUs.

#define IC    2048
#define NC    32
#define OD    16
#define JD    512           // NC*OD
#define NIC   256           // i-chunks
#define IPB   (IC/NIC)      // 8 capsules per k_pass block
#define EPS_SQ 1e-7f

typedef short  s16x4  __attribute__((ext_vector_type(4)));
typedef short  s16x8  __attribute__((ext_vector_type(8)));
typedef float  f32x16 __attribute__((ext_vector_type(16)));

__device__ inline short bfc(float f) {
  unsigned u = __builtin_bit_cast(unsigned, f);
  unsigned r = (u + 0x7FFFu + ((u >> 16) & 1u)) >> 16;
  return (short)(unsigned short)r;
}
__device__ inline float bf2f(short s) {
  return __builtin_bit_cast(float, ((unsigned)(unsigned short)s) << 16);
}
__device__ inline f32x16 fz16() {
  f32x16 z;
#pragma unroll
  for (int q = 0; q < 16; q++) z[q] = 0.f;
  return z;
}

// ---------------------------------------------------------------------------
// Pack x (fp32 [64][2048][16]) into MFMA B-fragments (bf16):
// xp[i][bg][lane][e], e0-3: k=4*hi+e ; e4-7: k=8+4*hi+(e-4)   (hi = lane>>5)
// ---------------------------------------------------------------------------
__global__ __launch_bounds__(256) void k_prep_x(const float* __restrict__ x,
                                                unsigned short* __restrict__ xp) {
  int t = blockIdx.x * 256 + threadIdx.x;   // IC*2*64 = 262144
  int l  = t & 63;
  int bg = (t >> 6) & 1;
  int i  = t >> 7;
  int b  = bg * 32 + (l & 31);
  int hi = l >> 5;
  const float* s = x + ((size_t)b * IC + i) * 16 + 4 * hi;
  float4 v0 = *(const float4*)(s);
  float4 v1 = *(const float4*)(s + 8);
  s16x8 r;
  r[0] = bfc(v0.x); r[1] = bfc(v0.y); r[2] = bfc(v0.z); r[3] = bfc(v0.w);
  r[4] = bfc(v1.x); r[5] = bfc(v1.y); r[6] = bfc(v1.z); r[7] = bfc(v1.w);
  *(s16x8*)(xp + (size_t)t * 8) = r;
}

// ---------------------------------------------------------------------------
// Pack W (fp32 [2048][512][16]) into bf16 A-fragments, coalesced both sides.
// Wp frag id = (i*16 + mt)*64 + l ; 8 bf16 per frag (16 B).
// Frag (mt,l): jd = mt*32 + (l&31), k = 4hi..4hi+3 and 8+4hi..8+4hi+3.
// ---------------------------------------------------------------------------
__global__ __launch_bounds__(256) void k_prep_w(const float* __restrict__ W,
                                                unsigned short* __restrict__ wp) {
  __shared__ unsigned lds[512 * 9];          // [jd][8 u32 (k-pairs)] + pad
  const int i = blockIdx.x;
  const int t = threadIdx.x;
  const float* src = W + (size_t)i * 8192;
#pragma unroll
  for (int q = 0; q < 8; q++) {
    int idx = q * 256 + t;                   // float4 index 0..2047 (coalesced)
    float4 v = *(const float4*)(src + (size_t)idx * 4);
    unsigned p0 = ((unsigned)(unsigned short)bfc(v.x)) |
                  (((unsigned)(unsigned short)bfc(v.y)) << 16);
    unsigned p1 = ((unsigned)(unsigned short)bfc(v.z)) |
                  (((unsigned)(unsigned short)bfc(v.w)) << 16);
    int jd = idx >> 2;
    int slot = (idx & 3) * 2;
    lds[jd * 9 + slot]     = p0;
    lds[jd * 9 + slot + 1] = p1;
  }
  __syncthreads();
#pragma unroll
  for (int q = 0; q < 4; q++) {
    int f = q * 256 + t;                     // frag index 0..1023 (coalesced)
    int mt = f >> 6, l = f & 63;
    int col = l & 31, hi = l >> 5;
    int jd = mt * 32 + col;
    unsigned r0 = lds[jd * 9 + 2 * hi];
    unsigned r1 = lds[jd * 9 + 2 * hi + 1];
    unsigned r2 = lds[jd * 9 + 2 * hi + 4];
    unsigned r3 = lds[jd * 9 + 2 * hi + 5];
    uint4 o; o.x = r0; o.y = r1; o.z = r2; o.w = r3;
    *(uint4*)(wp + ((size_t)i * 1024 + f) * 8) = o;
  }
}

// ---------------------------------------------------------------------------
// One routing pass. Grid 512 (bg = bid&1, ic = bid>>1), 256 thr (4 waves).
// Wave w owns mt = 4w..4w+3 (32 jd rows each); lane col = b-local.
// ---------------------------------------------------------------------------
template <bool FIRST, bool PACKED>
__global__ __launch_bounds__(256, 2) void k_pass(const float* __restrict__ W,
                                                 const unsigned short* __restrict__ Wp,
                                                 const unsigned short* __restrict__ xp,
                                                 const float* __restrict__ ST,
                                                 _Float16* __restrict__ part) {
  __shared__ float lg[32][33];
  const int bid = blockIdx.x;
  const int bg  = bid & 1;
  const int ic  = bid >> 1;
  const int tid = threadIdx.x;
  const int w   = tid >> 6;
  const int l   = tid & 63;
  const int col = l & 31;
  const int hi  = l >> 5;

  f32x16 sa[4];
#pragma unroll
  for (int m = 0; m < 4; m++) sa[m] = fz16();

  // S (cumulative outputs), packed bf16: svA = acc rows r0..7, svB = r8..15
  s16x8 svA[4], svB[4];
  if (!FIRST) {
#pragma unroll
    for (int m = 0; m < 4; m++) {
      int mt = w * 4 + m;
#pragma unroll
      for (int r = 0; r < 16; r++) {
        int row = (r & 3) + 8 * (r >> 2) + 4 * hi;
        float v = ST[(size_t)(mt * 32 + row) * 64 + bg * 32 + col];
        short h = bfc(v);
        if (r < 8) svA[m][r] = h; else svB[m][r - 8] = h;
      }
    }
  }

  for (int ii = 0; ii < IPB; ii++) {
    int i = ic * IPB + ii;
    s16x8 xv = *(const s16x8*)(xp + ((size_t)i * 2 + bg) * 512 + (size_t)l * 8);
    s16x4 xlo = __builtin_shufflevector(xv, xv, 0, 1, 2, 3);
    s16x4 xhi = __builtin_shufflevector(xv, xv, 4, 5, 6, 7);

    s16x4 wlo[4], whi[4];
    if (PACKED) {
#pragma unroll
      for (int m = 0; m < 4; m++) {
        s16x8 wv = *(const s16x8*)(Wp + ((size_t)i * 1024 + (w * 4 + m) * 64 + l) * 8);
        wlo[m] = __builtin_shufflevector(wv, wv, 0, 1, 2, 3);
        whi[m] = __builtin_shufflevector(wv, wv, 4, 5, 6, 7);
      }
    } else {
#pragma unroll
      for (int m = 0; m < 4; m++) {
        int jd = (w * 4 + m) * 32 + col;
        const float* wq = W + ((size_t)i * JD + jd) * 16 + 4 * hi;
        float4 a0 = *(const float4*)(wq);
        float4 a1 = *(const float4*)(wq + 8);
        s16x4 t0; t0[0]=bfc(a0.x); t0[1]=bfc(a0.y); t0[2]=bfc(a0.z); t0[3]=bfc(a0.w);
        s16x4 t1; t1[0]=bfc(a1.x); t1[1]=bfc(a1.y); t1[2]=bfc(a1.z); t1[3]=bfc(a1.w);
        wlo[m] = t0; whi[m] = t1;
      }
    }

    f32x16 D[4];
#pragma unroll
    for (int m = 0; m < 4; m++) {
      f32x16 acc = FIRST ? sa[m] : fz16();
      acc = __builtin_amdgcn_mfma_f32_32x32x8bf16_1k(wlo[m], xlo, acc, 0, 0, 0);
      acc = __builtin_amdgcn_mfma_f32_32x32x8bf16_1k(whi[m], xhi, acc, 0, 0, 0);
      if (FIRST) sa[m] = acc; else D[m] = acc;
    }

    if (!FIRST) {
      // logits: rows r<8 -> j even (2mt), r>=8 -> j odd (2mt+1)
#pragma unroll
      for (int m = 0; m < 4; m++) {
        float pe = 0.f, po = 0.f;
#pragma unroll
        for (int r = 0; r < 8; r++)  pe += D[m][r]     * bf2f(svA[m][r]);
#pragma unroll
        for (int r = 0; r < 8; r++)  po += D[m][r + 8] * bf2f(svB[m][r]);
        pe += __shfl_xor(pe, 32);   // other d-half in lane^32
        po += __shfl_xor(po, 32);
        int mt = w * 4 + m;
        if (l < 32) { lg[2 * mt][col] = pe; lg[2 * mt + 1][col] = po; }
      }
      __syncthreads();
      // softmax over j=32 per b: wave w handles b-local 8w..8w+7, 8 lanes/b
      {
        int bb = w * 8 + (l >> 3);
        int sub = l & 7;
        float v0 = lg[sub * 4 + 0][bb], v1 = lg[sub * 4 + 1][bb];
        float v2 = lg[sub * 4 + 2][bb], v3 = lg[sub * 4 + 3][bb];
        float mx = fmaxf(fmaxf(v0, v1), fmaxf(v2, v3));
        mx = fmaxf(mx, __shfl_xor(mx, 1));
        mx = fmaxf(mx, __shfl_xor(mx, 2));
        mx = fmaxf(mx, __shfl_xor(mx, 4));
        v0 = __expf(v0 - mx); v1 = __expf(v1 - mx);
        v2 = __expf(v2 - mx); v3 = __expf(v3 - mx);
        float sm = v0 + v1 + v2 + v3;
        sm += __shfl_xor(sm, 1);
        sm += __shfl_xor(sm, 2);
        sm += __shfl_xor(sm, 4);
        float iv = 1.0f / sm;
        lg[sub * 4 + 0][bb] = v0 * iv; lg[sub * 4 + 1][bb] = v1 * iv;
        lg[sub * 4 + 2][bb] = v2 * iv; lg[sub * 4 + 3][bb] = v3 * iv;
      }
      __syncthreads();
#pragma unroll
      for (int m = 0; m < 4; m++) {
        int mt = w * 4 + m;
        float ce = lg[2 * mt][col];
        float co = lg[2 * mt + 1][col];
#pragma unroll
        for (int r = 0; r < 8; r++)  sa[m][r]     += ce * D[m][r];
#pragma unroll
        for (int r = 0; r < 8; r++)  sa[m][r + 8] += co * D[m][r + 8];
      }
      __syncthreads();   // protect lg before next i overwrites it
    }
  }

  const float sc = FIRST ? (1.0f / 32.0f) : 1.0f;
#pragma unroll
  for (int m = 0; m < 4; m++) {
    int mt = w * 4 + m;
#pragma unroll
    for (int r = 0; r < 16; r++) {
      int row = (r & 3) + 8 * (r >> 2) + 4 * hi;
      int jd = mt * 32 + row;
      part[(((size_t)bg * JD + jd) * NIC + ic) * 32 + col] = (_Float16)(sa[m][r] * sc);
    }
  }
}

// ---------------------------------------------------------------------------
// Stage-1 reduction: 512 blocks (bg, j, q=ic/32), 512 thr (b = t&31, d = t>>5).
// ---------------------------------------------------------------------------
__global__ __launch_bounds__(512) void k_red(const _Float16* __restrict__ part,
                                             float* __restrict__ red) {
  int bid = blockIdx.x;
  int bg = bid & 1, j = (bid >> 1) & 31, q = bid >> 6;
  int t = threadIdx.x;
  int b = t & 31, d = t >> 5;
  int jd = j * 16 + d;
  const _Float16* p = part + (((size_t)(bg * JD + jd) * NIC) + q * 32) * 32 + b;
  float a0 = 0.f, a1 = 0.f, a2 = 0.f, a3 = 0.f;
#pragma unroll
  for (int qq = 0; qq < 32; qq += 4) {
    a0 += (float)p[(size_t)(qq + 0) * 32];
    a1 += (float)p[(size_t)(qq + 1) * 32];
    a2 += (float)p[(size_t)(qq + 2) * 32];
    a3 += (float)p[(size_t)(qq + 3) * 32];
  }
  red[((size_t)(bg * 32 + j) * 8 + q) * 512 + t] = (a0 + a1) + (a2 + a3);
}

// ---------------------------------------------------------------------------
// Stage-2: finish reduction (8 values), squash, update ST / final out.
// Grid 64 (bg = bid&1, j = bid>>1), 512 thr.
// ---------------------------------------------------------------------------
template <bool FIRST, bool FINAL>
__global__ __launch_bounds__(512) void k_squash2(const float* __restrict__ red,
                                                 float* __restrict__ ST,
                                                 float* __restrict__ out) {
  __shared__ float sl[16][33];
  int bid = blockIdx.x;
  int bg = bid & 1, j = bid >> 1;
  int t = threadIdx.x;
  int b = t & 31, d = t >> 5;
  float s = 0.f;
#pragma unroll
  for (int q = 0; q < 8; q++) s += red[((size_t)(bg * 32 + j) * 8 + q) * 512 + t];
  sl[d][b] = s * s;
  __syncthreads();
  float s2 = 0.f;
#pragma unroll
  for (int dd = 0; dd < 16; dd++) s2 += sl[dd][b];
  float o = s * s2 / ((1.0f + s2) * sqrtf(s2 + EPS_SQ));
  int jd = j * 16 + d;
  if (FINAL) {
    out[((size_t)(bg * 32 + b) * NC + j) * OD + d] = o;
  } else if (FIRST) {
    ST[(size_t)jd * 64 + bg * 32 + b] = o;
  } else {
    ST[(size_t)jd * 64 + bg * 32 + b] += o;
  }
}

// ---------------------------------------------------------------------------
extern "C" void kernel_launch(void* const* d_in, const int* in_sizes, int n_in,
                              void* d_out, int out_size, void* d_ws, size_t ws_size,
                              hipStream_t stream) {
  (void)in_sizes; (void)n_in; (void)out_size;
  const float* x = (const float*)d_in[0];
  const float* W = (const float*)d_in[1];
  float* out = (float*)d_out;

  const size_t off_xp  = 0;                                   // 4 MB
  const size_t off_st  = (size_t)4 << 20;                     // 128 KB (pad 256K)
  const size_t off_red = off_st + ((size_t)256 << 10);        // 1 MB
  const size_t off_pt  = off_red + ((size_t)1 << 20);         // 16.75 MB
  const size_t off_wp  = off_pt + (size_t)2 * JD * NIC * 32 * sizeof(_Float16);
  const size_t need_base = off_wp + 1024;
  const size_t need_full = off_wp + (size_t)IC * 1024 * 16 + 1024;
  fprintf(stderr, "[caps] ws_size=%zu need_base=%zu need_full=%zu\n",
          ws_size, need_base, need_full);
  if (ws_size < need_base) return;
  const bool packed = (ws_size >= need_full);

  unsigned short* xp = (unsigned short*)((char*)d_ws + off_xp);
  float*          ST = (float*)((char*)d_ws + off_st);
  float*         red = (float*)((char*)d_ws + off_red);
  _Float16*     part = (_Float16*)((char*)d_ws + off_pt);
  unsigned short* Wp = (unsigned short*)((char*)d_ws + off_wp);

  k_prep_x<<<dim3(1024), dim3(256), 0, stream>>>(x, xp);
  if (packed) {
    k_prep_w<<<dim3(2048), dim3(256), 0, stream>>>(W, Wp);
    k_pass<true, true><<<dim3(512), dim3(256), 0, stream>>>(W, Wp, xp, ST, part);
  } else {
    k_pass<true, false><<<dim3(512), dim3(256), 0, stream>>>(W, Wp, xp, ST, part);
  }
  k_red<<<dim3(512), dim3(512), 0, stream>>>(part, red);
  k_squash2<true, false><<<dim3(64), dim3(512), 0, stream>>>(red, ST, out);

  for (int pass = 1; pass < 3; pass++) {
    if (packed) {
      k_pass<false, true><<<dim3(512), dim3(256), 0, stream>>>(W, Wp, xp, ST, part);
    } else {
      k_pass<false, false><<<dim3(512), dim3(256), 0, stream>>>(W, Wp, xp, ST, part);
    }
    k_red<<<dim3(512), dim3(512), 0, stream>>>(part, red);
    if (pass == 1) {
      k_squash2<false, false><<<dim3(64), dim3(512), 0, stream>>>(red, ST, out);
    } else {
      k_squash2<false, true><<<dim3(64), dim3(512), 0, stream>>>(red, ST, out);
    }
  }
}

// Round 3
// 185.738 us; speedup vs baseline: 1.1698x; 1.0239x over previous
//
#include <hip/hip_runtime.h>
#include <cstdio>

// CapsuleLayer dynamic routing, MI355X (gfx950). Round 3.
//  - Round-2 diagnosis: k_pass<false> ~43us each despite packed W. The cost is
//    the 3-barrier / 2-full-LDS-exchange softmax per i-iteration, not W loads.
//  - Fix: softmax without max-subtraction (logits bounded ~|16|, fp32-safe).
//    Each wave exponentiates its 8 logits in-register; only the partial
//    partition sum Z (4 waves x 32 b floats) goes through LDS. Double-buffered
//    zbuf -> exactly ONE __syncthreads per i-iteration.
//  - k_prep_x folded into k_prep_w grid (one fewer serial launch).
//  - k_red: one block per (bg,jd) finishes the whole ic-reduction.

#define IC    2048
#define NC    32
#define OD    16
#define JD    512           // NC*OD
#define NIC   256           // i-chunks
#define IPB   (IC/NIC)      // 8 capsules per k_pass block
#define EPS_SQ 1e-7f

typedef short  s16x4  __attribute__((ext_vector_type(4)));
typedef short  s16x8  __attribute__((ext_vector_type(8)));
typedef float  f32x16 __attribute__((ext_vector_type(16)));

__device__ inline short bfc(float f) {
  unsigned u = __builtin_bit_cast(unsigned, f);
  unsigned r = (u + 0x7FFFu + ((u >> 16) & 1u)) >> 16;
  return (short)(unsigned short)r;
}
__device__ inline f32x16 fz16() {
  f32x16 z;
#pragma unroll
  for (int q = 0; q < 16; q++) z[q] = 0.f;
  return z;
}

// ---------------------------------------------------------------------------
// Combined prep. Blocks 0..2047: pack W[i] (fp32, coalesced) -> bf16 MFMA
// A-fragments via LDS bounce. Blocks 2048..2559: pack x -> bf16 B-fragments.
// Wp frag (i, mt, l): jd = mt*32 + (l&31), k = 4hi..4hi+3 and 8+4hi..+3.
// xp[i][bg][l][e]:   b = bg*32 + (l&31),  same k split (hi = l>>5).
// ---------------------------------------------------------------------------
__global__ __launch_bounds__(256) void k_prep(const float* __restrict__ W,
                                              const float* __restrict__ x,
                                              unsigned short* __restrict__ wp,
                                              unsigned short* __restrict__ xp) {
  __shared__ unsigned lds[512 * 9];          // [jd][8 u32 k-pairs] + pad
  const int bid = blockIdx.x;
  const int t = threadIdx.x;
  if (bid < 2048) {
    const int i = bid;
    const float* src = W + (size_t)i * 8192;
#pragma unroll
    for (int q = 0; q < 8; q++) {
      int idx = q * 256 + t;                 // float4 idx 0..2047 (coalesced)
      float4 v = *(const float4*)(src + (size_t)idx * 4);
      unsigned p0 = ((unsigned)(unsigned short)bfc(v.x)) |
                    (((unsigned)(unsigned short)bfc(v.y)) << 16);
      unsigned p1 = ((unsigned)(unsigned short)bfc(v.z)) |
                    (((unsigned)(unsigned short)bfc(v.w)) << 16);
      int jd = idx >> 2;
      int slot = (idx & 3) * 2;
      lds[jd * 9 + slot]     = p0;
      lds[jd * 9 + slot + 1] = p1;
    }
    __syncthreads();
#pragma unroll
    for (int q = 0; q < 4; q++) {
      int f = q * 256 + t;                   // frag 0..1023 (coalesced write)
      int mt = f >> 6, l = f & 63;
      int col = l & 31, hi = l >> 5;
      int jd = mt * 32 + col;
      uint4 o;
      o.x = lds[jd * 9 + 2 * hi];
      o.y = lds[jd * 9 + 2 * hi + 1];
      o.z = lds[jd * 9 + 2 * hi + 4];
      o.w = lds[jd * 9 + 2 * hi + 5];
      *(uint4*)(wp + ((size_t)i * 1024 + f) * 8) = o;
    }
  } else {
    int base = (bid - 2048) * 512;
#pragma unroll
    for (int it = 0; it < 2; it++) {
      int tt = base + it * 256 + t;          // 0..262143
      int l  = tt & 63;
      int bg = (tt >> 6) & 1;
      int i  = tt >> 7;
      int b  = bg * 32 + (l & 31);
      int hi = l >> 5;
      const float* s = x + ((size_t)b * IC + i) * 16 + 4 * hi;
      float4 v0 = *(const float4*)(s);
      float4 v1 = *(const float4*)(s + 8);
      s16x8 r;
      r[0] = bfc(v0.x); r[1] = bfc(v0.y); r[2] = bfc(v0.z); r[3] = bfc(v0.w);
      r[4] = bfc(v1.x); r[5] = bfc(v1.y); r[6] = bfc(v1.z); r[7] = bfc(v1.w);
      *(s16x8*)(xp + (size_t)tt * 8) = r;
    }
  }
}

// ---------------------------------------------------------------------------
// One routing pass. Grid 512 (bg = bid&1, ic = bid>>1), 256 thr (4 waves).
// Wave w owns mt = 4w..4w+3 (32 jd rows each); lane col (=l&31) = b-local.
// Acc row mapping (32x32x8bf16_1k): row = (r&3) + 8*(r>>2) + 4*hi.
// rows r<8 -> j = 2mt (even d-half pair j), r>=8 -> j = 2mt+1.
// Softmax: no max-subtract (logits bounded); only partial-Z crosses waves.
// ---------------------------------------------------------------------------
template <bool FIRST>
__global__ __launch_bounds__(256, 2) void k_pass(const unsigned short* __restrict__ Wp,
                                                 const unsigned short* __restrict__ xp,
                                                 const float* __restrict__ ST,
                                                 _Float16* __restrict__ part) {
  __shared__ float zbuf[2][4][33];           // [parity][wave][b-local]
  const int bid = blockIdx.x;
  const int bg  = bid & 1;
  const int ic  = bid >> 1;
  const int tid = threadIdx.x;
  const int w   = tid >> 6;
  const int l   = tid & 63;
  const int col = l & 31;
  const int hi  = l >> 5;

  f32x16 sa[4];
#pragma unroll
  for (int m = 0; m < 4; m++) sa[m] = fz16();

  float Sv[4][16];
  if (!FIRST) {
#pragma unroll
    for (int m = 0; m < 4; m++) {
      int mt = w * 4 + m;
#pragma unroll
      for (int r = 0; r < 16; r++) {
        int row = (r & 3) + 8 * (r >> 2) + 4 * hi;
        Sv[m][r] = ST[(size_t)(mt * 32 + row) * 64 + bg * 32 + col];
      }
    }
  }

  for (int ii = 0; ii < IPB; ii++) {
    int i = ic * IPB + ii;
    s16x8 xv = *(const s16x8*)(xp + ((size_t)i * 2 + bg) * 512 + (size_t)l * 8);
    s16x4 xlo = __builtin_shufflevector(xv, xv, 0, 1, 2, 3);
    s16x4 xhi = __builtin_shufflevector(xv, xv, 4, 5, 6, 7);

    s16x4 wlo[4], whi[4];
#pragma unroll
    for (int m = 0; m < 4; m++) {
      s16x8 wv = *(const s16x8*)(Wp + ((size_t)i * 1024 + (w * 4 + m) * 64 + l) * 8);
      wlo[m] = __builtin_shufflevector(wv, wv, 0, 1, 2, 3);
      whi[m] = __builtin_shufflevector(wv, wv, 4, 5, 6, 7);
    }

    if (FIRST) {
#pragma unroll
      for (int m = 0; m < 4; m++) {
        sa[m] = __builtin_amdgcn_mfma_f32_32x32x8bf16_1k(wlo[m], xlo, sa[m], 0, 0, 0);
        sa[m] = __builtin_amdgcn_mfma_f32_32x32x8bf16_1k(whi[m], xhi, sa[m], 0, 0, 0);
      }
    } else {
      f32x16 D[4];
#pragma unroll
      for (int m = 0; m < 4; m++) {
        f32x16 acc = fz16();
        acc = __builtin_amdgcn_mfma_f32_32x32x8bf16_1k(wlo[m], xlo, acc, 0, 0, 0);
        D[m] = __builtin_amdgcn_mfma_f32_32x32x8bf16_1k(whi[m], xhi, acc, 0, 0, 0);
      }

      // logits (both d-halves summed via lane^32), exp in-register
      float ee[4], eo[4];
      float zl = 0.f;
#pragma unroll
      for (int m = 0; m < 4; m++) {
        float pe = 0.f, po = 0.f;
#pragma unroll
        for (int r = 0; r < 8; r++) pe += D[m][r]     * Sv[m][r];
#pragma unroll
        for (int r = 0; r < 8; r++) po += D[m][r + 8] * Sv[m][r + 8];
        pe += __shfl_xor(pe, 32);
        po += __shfl_xor(po, 32);
        ee[m] = __expf(pe);
        eo[m] = __expf(po);
        zl += ee[m] + eo[m];
      }
      // exchange ONLY the partial partition sums (4 waves x 32 b)
      if (l < 32) zbuf[ii & 1][w][col] = zl;
      __syncthreads();
      float Z = zbuf[ii & 1][0][col] + zbuf[ii & 1][1][col] +
                zbuf[ii & 1][2][col] + zbuf[ii & 1][3][col];
      float rz = 1.0f / Z;
#pragma unroll
      for (int m = 0; m < 4; m++) {
        float ce = ee[m] * rz;
        float co = eo[m] * rz;
#pragma unroll
        for (int r = 0; r < 8; r++) sa[m][r]     += ce * D[m][r];
#pragma unroll
        for (int r = 0; r < 8; r++) sa[m][r + 8] += co * D[m][r + 8];
      }
    }
  }

  const float sc = FIRST ? (1.0f / 32.0f) : 1.0f;
#pragma unroll
  for (int m = 0; m < 4; m++) {
    int mt = w * 4 + m;
#pragma unroll
    for (int r = 0; r < 16; r++) {
      int row = (r & 3) + 8 * (r >> 2) + 4 * hi;
      int jd = mt * 32 + row;
      part[(((size_t)bg * JD + jd) * NIC + ic) * 32 + col] = (_Float16)(sa[m][r] * sc);
    }
  }
}

// ---------------------------------------------------------------------------
// Full ic-reduction: one block per (bg,jd). 256 thr: b = t&31, g = t>>5 (8
// groups), each sums 32 ic values (stride 8). Output s_red[bg][jd][b] fp32.
// ---------------------------------------------------------------------------
__global__ __launch_bounds__(256) void k_red(const _Float16* __restrict__ part,
                                             float* __restrict__ s_red) {
  __shared__ float sl[8][33];
  int bid = blockIdx.x;
  int bg = bid & 1, jd = bid >> 1;
  int t = threadIdx.x;
  int b = t & 31, g = t >> 5;
  const _Float16* p = part + ((size_t)(bg * JD + jd) * NIC + g) * 32 + b;
  float a0 = 0.f, a1 = 0.f, a2 = 0.f, a3 = 0.f;
#pragma unroll
  for (int q = 0; q < 32; q += 4) {
    a0 += (float)p[(size_t)(q + 0) * 8 * 32];
    a1 += (float)p[(size_t)(q + 1) * 8 * 32];
    a2 += (float)p[(size_t)(q + 2) * 8 * 32];
    a3 += (float)p[(size_t)(q + 3) * 8 * 32];
  }
  sl[g][b] = (a0 + a1) + (a2 + a3);
  __syncthreads();
  if (t < 32) {
    float s = 0.f;
#pragma unroll
    for (int gg = 0; gg < 8; gg++) s += sl[gg][t];
    s_red[((size_t)bg * JD + jd) * 32 + t] = s;
  }
}

// ---------------------------------------------------------------------------
// Squash + ST update / final out. Grid 64 (bg, j), 512 thr (b = t&31, d = t>>5).
// ---------------------------------------------------------------------------
template <bool FIRST, bool FINAL>
__global__ __launch_bounds__(512) void k_squash(const float* __restrict__ s_red,
                                                float* __restrict__ ST,
                                                float* __restrict__ out) {
  __shared__ float sl[16][33];
  int bid = blockIdx.x;
  int bg = bid & 1, j = bid >> 1;
  int t = threadIdx.x;
  int b = t & 31, d = t >> 5;
  int jd = j * 16 + d;
  float s = s_red[((size_t)bg * JD + jd) * 32 + b];
  sl[d][b] = s * s;
  __syncthreads();
  float s2 = 0.f;
#pragma unroll
  for (int dd = 0; dd < 16; dd++) s2 += sl[dd][b];
  float o = s * s2 / ((1.0f + s2) * sqrtf(s2 + EPS_SQ));
  if (FINAL) {
    out[((size_t)(bg * 32 + b) * NC + j) * OD + d] = o;
  } else if (FIRST) {
    ST[(size_t)jd * 64 + bg * 32 + b] = o;
  } else {
    ST[(size_t)jd * 64 + bg * 32 + b] += o;
  }
}

// ---------------------------------------------------------------------------
extern "C" void kernel_launch(void* const* d_in, const int* in_sizes, int n_in,
                              void* d_out, int out_size, void* d_ws, size_t ws_size,
                              hipStream_t stream) {
  (void)in_sizes; (void)n_in; (void)out_size;
  const float* x = (const float*)d_in[0];
  const float* W = (const float*)d_in[1];
  float* out = (float*)d_out;

  const size_t off_xp  = 0;                                   // 4 MB
  const size_t off_st  = (size_t)4 << 20;                     // 128 KB
  const size_t off_sr  = off_st + ((size_t)256 << 10);        // 256 KB
  const size_t off_pt  = off_sr + ((size_t)512 << 10);        // 16.75 MB
  const size_t off_wp  = off_pt + (size_t)2 * JD * NIC * 32 * sizeof(_Float16);
  const size_t need = off_wp + (size_t)IC * 1024 * 16 + 1024; // ~88.5 MB
  fprintf(stderr, "[caps] ws_size=%zu need=%zu\n", ws_size, need);
  if (ws_size < need) return;

  unsigned short* xp = (unsigned short*)((char*)d_ws + off_xp);
  float*          ST = (float*)((char*)d_ws + off_st);
  float*       s_red = (float*)((char*)d_ws + off_sr);
  _Float16*     part = (_Float16*)((char*)d_ws + off_pt);
  unsigned short* Wp = (unsigned short*)((char*)d_ws + off_wp);

  k_prep<<<dim3(2560), dim3(256), 0, stream>>>(W, x, Wp, xp);

  k_pass<true><<<dim3(512), dim3(256), 0, stream>>>(Wp, xp, ST, part);
  k_red<<<dim3(1024), dim3(256), 0, stream>>>(part, s_red);
  k_squash<true, false><<<dim3(64), dim3(512), 0, stream>>>(s_red, ST, out);

  k_pass<false><<<dim3(512), dim3(256), 0, stream>>>(Wp, xp, ST, part);
  k_red<<<dim3(1024), dim3(256), 0, stream>>>(part, s_red);
  k_squash<false, false><<<dim3(64), dim3(512), 0, stream>>>(s_red, ST, out);

  k_pass<false><<<dim3(512), dim3(256), 0, stream>>>(Wp, xp, ST, part);
  k_red<<<dim3(1024), dim3(256), 0, stream>>>(part, s_red);
  k_squash<false, true><<<dim3(64), dim3(512), 0, stream>>>(s_red, ST, out);
}